// Round 7
// baseline (168.277 us; speedup 1.0000x reference)
//
#include <hip/hip_runtime.h>
#include <math.h>

constexpr int NROW = 8192;
constexpr int FD   = 256;

// ws layout (bytes), ws_size = 256 MiB (measured via harness poison fill):
//   0        scal[8]
//   4096     nrm0[8192]     (32 KB)
//   36864    nrm1[8192]     (32 KB)
//   69632    fpart[2048]    (8 KB)
//   77824    fpart1[1024]   (4 KB)
//   81920    cpart[64*256]  (64 KB) ends 147456
//   147456   c0[256]
//   148480   u[8192]        (32 KB) ends 181248
//   181248   svec[256]
//   182272   vvec[256]
//   262144   G0[65536]      (256 KB) ends 524288
//   524288   vpart[512*256] (512 KB) ends 1048576
//   1048576  emb[8192*256]  (8 MB)  ends 9437184
//   9437184  cpart1[1024*256] (1 MB) ends 10485760
//   10485760 wpart1[1024*256] (1 MB) ends 11534336
//   16777216 Gp[64*65536]   (16 MB) ends 33554432

__device__ __forceinline__ float f_of(float nj, float A, float B, float AB) {
    float inner = AB * nj;
    return A - (inner <= 0.f ? inner : 0.f) * B;
}

// one wave per row: nrm0[j] = ||row||^2 ; block partial -> fpart
__global__ void k_norm(const float* __restrict__ in, float* __restrict__ nrm,
                       float* __restrict__ fpart) {
    __shared__ float bs[4];
    int wave = threadIdx.x >> 6, lane = threadIdx.x & 63;
    int row = blockIdx.x * 4 + wave;
    const float4 v = *(const float4*)&in[(size_t)row * FD + lane * 4];
    float s = v.x*v.x + v.y*v.y + v.z*v.z + v.w*v.w;
    #pragma unroll
    for (int off = 32; off; off >>= 1) s += __shfl_down(s, off);
    if (lane == 0) { nrm[row] = s; bs[wave] = s; }
    __syncthreads();
    if (threadIdx.x == 0) fpart[blockIdx.x] = bs[0] + bs[1] + bs[2] + bs[3];
}

// 1 block: a,b dots; F2 = sum(fpart); scalars A,B,AB for depth 0
__global__ void k_red(const float* __restrict__ fpart, int n, float* __restrict__ scal,
                      const float* __restrict__ linear, const float* __restrict__ dirv,
                      const float* __restrict__ feat) {
    __shared__ float l[256];
    int tid = threadIdx.x;
    if (tid < 64) {
        for (int i = 0; i < 2; ++i) {
            float pa = 0.f, pb = 0.f;
            for (int k = tid; k < FD; k += 64) {
                float ll = linear[i*FD + k];
                pa += feat[i*FD + k] * ll;
                pb += dirv[i*FD + k] * ll;
            }
            #pragma unroll
            for (int off = 32; off; off >>= 1) {
                pa += __shfl_down(pa, off);
                pb += __shfl_down(pb, off);
            }
            if (tid == 0) { scal[i] = pa; scal[2 + i] = pb; }
        }
    }
    float s = 0.f;
    for (int j = tid; j < n; j += 256) s += fpart[j];
    l[tid] = s;
    __syncthreads();
    for (int off = 128; off; off >>= 1) {
        if (tid < off) l[tid] += l[tid + off];
        __syncthreads();
    }
    if (tid == 0) {
        float F2 = l[0];
        float a = scal[0], b = scal[2];
        float sb = (b > 0.f) ? 1.f : ((b < 0.f) ? -1.f : 0.f);
        float B = sb / sqrtf(F2);
        scal[4] = a; scal[5] = B; scal[6] = a * B; scal[7] = F2;
    }
}

// Gram partials of r0 = f0*X: grid (4,4,NZ); 64x64 tile, 4x4 acc, KR=NROW/NZ rows/z.
// tj==0 blocks emit cpart[z][ti*64..+64] = colsum of scaled rows in their K-range.
__global__ void __launch_bounds__(256, 4)
k_gram(const float* __restrict__ X, const float* __restrict__ nrm0,
       const float* __restrict__ scal, float* __restrict__ Gp,
       float* __restrict__ cpart) {
    __shared__ float As[32][68];   // stride 68: b128 reads 2-way max (free)
    __shared__ float Bs[32][68];
    __shared__ float frows[256];
    const int ti = blockIdx.x, tj = blockIdx.y, z = blockIdx.z;
    const int KR = NROW / gridDim.z;
    const int m0 = z * KR;
    const int tid = threadIdx.x;
    const int tx = tid & 15, ty = tid >> 4;    // B cols tx*4, A cols ty*4
    const int p = tid & 63, q = tid >> 6;
    const float A = scal[4], B = scal[5], AB = scal[6];
    for (int i = tid; i < KR; i += 256) frows[i] = f_of(nrm0[m0 + i], A, B, AB);
    float acc[4][4] = {};
    float cs = 0.f;
    for (int mc = 0; mc < KR; mc += 32) {
        __syncthreads();
        #pragma unroll
        for (int r = 0; r < 2; ++r) {
            int idx = tid + r * 256;
            int mm = idx >> 4, c4 = (idx & 15) << 2;
            float f = frows[mc + mm];
            const float* rp = X + (size_t)(m0 + mc + mm) * FD;
            float4 a = *(const float4*)&rp[ti*64 + c4];
            float4 b = *(const float4*)&rp[tj*64 + c4];
            a.x *= f; a.y *= f; a.z *= f; a.w *= f;
            b.x *= f; b.y *= f; b.z *= f; b.w *= f;
            *(float4*)&As[mm][c4] = a;
            *(float4*)&Bs[mm][c4] = b;
        }
        __syncthreads();
        #pragma unroll 8
        for (int mm = 0; mm < 32; ++mm) {
            float4 a4 = *(const float4*)&As[mm][ty*4];
            float4 b4 = *(const float4*)&Bs[mm][tx*4];
            float av[4] = {a4.x, a4.y, a4.z, a4.w};
            float bv[4] = {b4.x, b4.y, b4.z, b4.w};
            #pragma unroll
            for (int r = 0; r < 4; ++r)
                #pragma unroll
                for (int cc = 0; cc < 4; ++cc)
                    acc[r][cc] += av[r] * bv[cc];
        }
        if (tj == 0) {
            #pragma unroll
            for (int s = 0; s < 8; ++s) cs += As[q*8 + s][p];
        }
    }
    float* gp = Gp + (size_t)z * (FD * FD);
    #pragma unroll
    for (int r = 0; r < 4; ++r) {
        float4 o = make_float4(acc[r][0], acc[r][1], acc[r][2], acc[r][3]);
        *(float4*)&gp[(ti*64 + ty*4 + r)*FD + tj*64 + tx*4] = o;
    }
    if (tj == 0) {
        __syncthreads();
        ((float*)As)[tid] = cs;            // tid = q*64 + p
        __syncthreads();
        if (tid < 64)
            cpart[z*FD + ti*64 + tid] = ((float*)As)[tid] + ((float*)As)[64 + tid] +
                                        ((float*)As)[128 + tid] + ((float*)As)[192 + tid];
    }
}

// blocks 0..255: G0 = sum_z Gp ; block 256: c0 = sum_z cpart
__global__ void k_gred(const float* __restrict__ Gp, const float* __restrict__ cpart,
                       float* __restrict__ G0, float* __restrict__ c0, int NZg) {
    int tid = threadIdx.x;
    if (blockIdx.x < 256) {
        int e0 = blockIdx.x * 256 + tid;
        float s = 0.f;
        #pragma unroll 8
        for (int z = 0; z < NZg; ++z) s += Gp[(size_t)z * (FD * FD) + e0];
        G0[e0] = s;
    } else {
        float s = 0.f;
        #pragma unroll 8
        for (int z = 0; z < NZg; ++z) s += cpart[z*FD + tid];
        c0[tid] = s;
    }
}

// emb'[j] = r_j + (r_j@G0 - (r_j.c0) r_j)/N , r_j = f0_j X_j.
// 256 thr, 8 rows/block, 1024 blocks. Emits nrm1, fpart1, and column partials
// cpart1[bid][col] = sum_j emb'[j][col], wpart1[bid][col] = sum_j nrm1_j emb'[j][col].
__global__ void __launch_bounds__(256, 4)
k_apply(const float* __restrict__ X, const float* __restrict__ nrm0,
        const float* __restrict__ scal, const float* __restrict__ G0,
        const float* __restrict__ c0, float* __restrict__ emb,
        float* __restrict__ nrm1, float* __restrict__ fpart1,
        float* __restrict__ cpart1, float* __restrict__ wpart1) {
    __shared__ float rows[8][FD + 4];
    __shared__ float csh[FD];
    __shared__ float tmp[4][FD];
    __shared__ float ff[8];
    __shared__ float u0[8];
    __shared__ float np[4][8];
    const int tid = threadIdx.x;
    const int r0 = blockIdx.x * 8;
    const float A = scal[4], B = scal[5], AB = scal[6];

    csh[tid] = c0[tid];
    if (tid < 8) ff[tid] = f_of(nrm0[r0 + tid], A, B, AB);
    __syncthreads();

    #pragma unroll
    for (int r = 0; r < 2; ++r) {
        int idx = tid + r * 256;
        int j = idx >> 6, c4 = (idx & 63) << 2;
        float4 v = *(const float4*)&X[(size_t)(r0 + j) * FD + c4];
        float f = ff[j];
        v.x *= f; v.y *= f; v.z *= f; v.w *= f;
        *(float4*)&rows[j][c4] = v;
    }
    __syncthreads();

    const int wave = tid >> 6, lane = tid & 63;
    #pragma unroll
    for (int jj = 0; jj < 2; ++jj) {
        int j = wave * 2 + jj;
        float4 rv = *(const float4*)&rows[j][lane*4];
        float4 cc = *(const float4*)&csh[lane*4];
        float s = rv.x*cc.x + rv.y*cc.y + rv.z*cc.z + rv.w*cc.w;
        #pragma unroll
        for (int off = 32; off; off >>= 1) s += __shfl_down(s, off);
        if (lane == 0) u0[j] = s;
    }
    __syncthreads();

    const int rq = lane >> 4, cx = lane & 15;
    const int c0w = wave * 64 + cx * 4;    // 4 output cols
    const int jb = rq * 2;                 // 2 rows
    float acc[2][4] = {};
    for (int m = 0; m < FD; m += 4) {
        float4 g0 = *(const float4*)&G0[(m+0)*FD + c0w];
        float4 g1 = *(const float4*)&G0[(m+1)*FD + c0w];
        float4 g2 = *(const float4*)&G0[(m+2)*FD + c0w];
        float4 g3 = *(const float4*)&G0[(m+3)*FD + c0w];
        #pragma unroll
        for (int jj = 0; jj < 2; ++jj) {
            float4 rv = *(const float4*)&rows[jb + jj][m];
            acc[jj][0] += rv.x*g0.x + rv.y*g1.x + rv.z*g2.x + rv.w*g3.x;
            acc[jj][1] += rv.x*g0.y + rv.y*g1.y + rv.z*g2.y + rv.w*g3.y;
            acc[jj][2] += rv.x*g0.z + rv.y*g1.z + rv.z*g2.z + rv.w*g3.z;
            acc[jj][3] += rv.x*g0.w + rv.y*g1.w + rv.z*g2.w + rv.w*g3.w;
        }
    }

    const float invN = 1.0f / NROW;
    float ssl[2];
    float4 ov[2];
    #pragma unroll
    for (int jj = 0; jj < 2; ++jj) {
        int j = jb + jj;
        float4 v = *(const float4*)&rows[j][c0w];
        float uj = u0[j];
        float4 o;
        o.x = v.x + (acc[jj][0] - uj*v.x) * invN;
        o.y = v.y + (acc[jj][1] - uj*v.y) * invN;
        o.z = v.z + (acc[jj][2] - uj*v.z) * invN;
        o.w = v.w + (acc[jj][3] - uj*v.w) * invN;
        *(float4*)&emb[(size_t)(r0 + j) * FD + c0w] = o;
        ov[jj] = o;
        ssl[jj] = o.x*o.x + o.y*o.y + o.z*o.z + o.w*o.w;
    }
    #pragma unroll
    for (int jj = 0; jj < 2; ++jj) {
        float s = ssl[jj];
        #pragma unroll
        for (int off = 8; off; off >>= 1) s += __shfl_down(s, off);
        if (cx == 0) np[wave][jb + jj] = s;
    }
    __syncthreads();
    if (tid < 8) {
        float nn = np[0][tid] + np[1][tid] + np[2][tid] + np[3][tid];
        nrm1[r0 + tid] = nn;
        ff[tid] = nn;                       // ff now holds nrm1 for the 8 rows
    }
    __syncthreads();
    if (tid == 0) {
        float fp = 0.f;
        #pragma unroll
        for (int j = 0; j < 8; ++j) fp += ff[j];
        fpart1[blockIdx.x] = fp;
    }
    // column partials from registers (2 rows per thread, 4 rq-groups)
    {
        float4 cp;
        cp.x = ov[0].x + ov[1].x; cp.y = ov[0].y + ov[1].y;
        cp.z = ov[0].z + ov[1].z; cp.w = ov[0].w + ov[1].w;
        *(float4*)&tmp[rq][c0w] = cp;
    }
    __syncthreads();
    cpart1[(size_t)blockIdx.x * FD + tid] =
        tmp[0][tid] + tmp[1][tid] + tmp[2][tid] + tmp[3][tid];
    {
        float n0 = ff[jb], n1 = ff[jb + 1];
        float4 wp;
        wp.x = n0*ov[0].x + n1*ov[1].x; wp.y = n0*ov[0].y + n1*ov[1].y;
        wp.z = n0*ov[0].z + n1*ov[1].z; wp.w = n0*ov[0].w + n1*ov[1].w;
        __syncthreads();
        *(float4*)&tmp[rq][c0w] = wp;
    }
    __syncthreads();
    wpart1[(size_t)blockIdx.x * FD + tid] =
        tmp[0][tid] + tmp[1][tid] + tmp[2][tid] + tmp[3][tid];
}

// depth-1 scalars from fpart1[1024]: A1, B1, AB1, kappa
__device__ __forceinline__ void red1_scal(const float* fpart1, const float* scal,
                                          float* l, float& A, float& B, float& AB,
                                          float& kap) {
    int tid = threadIdx.x;
    float s = fpart1[tid] + fpart1[tid + 256] + fpart1[tid + 512] + fpart1[tid + 768];
    l[tid] = s;
    __syncthreads();
    for (int off = 128; off; off >>= 1) {
        if (tid < off) l[tid] += l[tid + off];
        __syncthreads();
    }
    float F2 = l[0];
    float a = scal[1], b = scal[3];
    float sb = (b > 0.f) ? 1.f : ((b < 0.f) ? -1.f : 0.f);
    B = sb / sqrtf(F2);
    A = a; AB = a * B;
    kap = (AB <= 0.f) ? AB * B : 0.f;
    __syncthreads();
}

// svec[col] = A1 * sum_b cpart1[b][col] - kappa * sum_b wpart1[b][col]; 64 blocks
__global__ void k_sv(const float* __restrict__ fpart1, const float* __restrict__ scal,
                     const float* __restrict__ cpart1, const float* __restrict__ wpart1,
                     float* __restrict__ svec) {
    __shared__ float l[256];
    float A1, B1, AB1, kap;
    red1_scal(fpart1, scal, l, A1, B1, AB1, kap);
    int tid = threadIdx.x;
    int col = blockIdx.x * 4 + (tid >> 6);
    int lane = tid & 63;
    float cs = 0.f, wsm = 0.f;
    #pragma unroll 4
    for (int b = lane; b < 1024; b += 64) {
        cs  += cpart1[(size_t)b * FD + col];
        wsm += wpart1[(size_t)b * FD + col];
    }
    #pragma unroll
    for (int off = 32; off; off >>= 1) {
        cs  += __shfl_down(cs, off);
        wsm += __shfl_down(wsm, off);
    }
    if (lane == 0) svec[col] = A1 * cs - kap * wsm;
}

// u[row] = f1 (emb'_row . s) ; vpart[bid][col] = sum_j (u_j f1_j) emb'[j][col]
__global__ void k_uv(const float* __restrict__ emb, const float* __restrict__ nrm1,
                     const float* __restrict__ scal, const float* __restrict__ fpart1,
                     const float* __restrict__ svec, float* __restrict__ u,
                     float* __restrict__ vpart) {
    __shared__ float l[256];
    __shared__ float ssh[FD];
    __shared__ float uf[16];
    float A, B, AB, kap;
    red1_scal(fpart1, scal, l, A, B, AB, kap);
    int tid = threadIdx.x;
    int r0 = blockIdx.x * 16;
    ssh[tid] = svec[tid];
    __syncthreads();
    const int wave = tid >> 6, lane = tid & 63;
    float4 sv = *(const float4*)&ssh[lane*4];
    #pragma unroll
    for (int jj = 0; jj < 4; ++jj) {
        int row = r0 + wave * 4 + jj;
        float4 ev = *(const float4*)&emb[(size_t)row * FD + lane*4];
        float s = ev.x*sv.x + ev.y*sv.y + ev.z*sv.z + ev.w*sv.w;
        #pragma unroll
        for (int off = 32; off; off >>= 1) s += __shfl_down(s, off);
        if (lane == 0) {
            float f = A - kap * nrm1[row];
            float uj = f * s;
            u[row] = uj;
            uf[wave*4 + jj] = uj * f;
        }
    }
    __syncthreads();
    float vp = 0.f;
    #pragma unroll
    for (int j = 0; j < 16; ++j)
        vp += uf[j] * emb[(size_t)(r0 + j) * FD + tid];
    vpart[(size_t)blockIdx.x * FD + tid] = vp;
}

// reduce vpart[512][256] -> vvec[256]; grid 64 x 256 thr (4 cols/block)
__global__ void k_vred(const float* __restrict__ part, float* __restrict__ vec) {
    int tid = threadIdx.x;
    int col = blockIdx.x * 4 + (tid >> 6);
    int lane = tid & 63;
    float s = 0.f;
    #pragma unroll
    for (int b = 0; b < 8; ++b) s += part[(size_t)(b * 64 + lane) * FD + col];
    #pragma unroll
    for (int off = 32; off; off >>= 1) s += __shfl_down(s, off);
    if (lane == 0) vec[col] = s;
}

// out[row] = (u + (f1*(emb'_row . v) - u^2)/N)/N
__global__ void k_out(const float* __restrict__ emb, const float* __restrict__ nrm1,
                      const float* __restrict__ scal, const float* __restrict__ fpart1,
                      const float* __restrict__ vvec, const float* __restrict__ u,
                      float* __restrict__ out) {
    __shared__ float l[256];
    __shared__ float vsh[FD];
    float A, B, AB, kap;
    red1_scal(fpart1, scal, l, A, B, AB, kap);
    int tid = threadIdx.x;
    int r0 = blockIdx.x * 16;
    vsh[tid] = vvec[tid];
    __syncthreads();
    const int wave = tid >> 6, lane = tid & 63;
    const float invN = 1.0f / NROW;
    float4 vv = *(const float4*)&vsh[lane*4];
    #pragma unroll
    for (int jj = 0; jj < 4; ++jj) {
        int row = r0 + wave * 4 + jj;
        float4 ev = *(const float4*)&emb[(size_t)row * FD + lane*4];
        float s = ev.x*vv.x + ev.y*vv.y + ev.z*vv.z + ev.w*vv.w;
        #pragma unroll
        for (int off = 32; off; off >>= 1) s += __shfl_down(s, off);
        if (lane == 0 && row < NROW - 1) {
            float f = A - kap * nrm1[row];
            float uj = u[row];
            out[row] = (uj + (f * s - uj * uj) * invN) * invN;
        }
    }
}

extern "C" void kernel_launch(void* const* d_in, const int* in_sizes, int n_in,
                              void* d_out, int out_size, void* d_ws, size_t ws_size,
                              hipStream_t stream) {
    const float* X      = (const float*)d_in[0];
    // d_in[1] = coefs (unused by the reference forward)
    const float* linear = (const float*)d_in[2];
    const float* dirv   = (const float*)d_in[3];
    const float* feat   = (const float*)d_in[4];
    float* out = (float*)d_out;

    char* ws = (char*)d_ws;
    float* scal   = (float*)(ws + 0);
    float* nrm0   = (float*)(ws + 4096);
    float* nrm1   = (float*)(ws + 36864);
    float* fpart  = (float*)(ws + 69632);
    float* fpart1 = (float*)(ws + 77824);
    float* cpart  = (float*)(ws + 81920);
    float* c0     = (float*)(ws + 147456);
    float* u      = (float*)(ws + 148480);
    float* svec   = (float*)(ws + 181248);
    float* vvec   = (float*)(ws + 182272);
    float* G0     = (float*)(ws + 262144);
    float* vpart  = (float*)(ws + 524288);
    float* emb    = (float*)(ws + 1048576);
    float* cpart1 = (float*)(ws + 9437184);
    float* wpart1 = (float*)(ws + 10485760);

    // Gram partials: NZ=64 in dedicated 16 MB region (ws measured at 256 MiB);
    // fallback NZ=32 aliasing emb if ws is unexpectedly small.
    int NZg;
    float* Gp;
    if (ws_size >= (size_t)33554432) { NZg = 64; Gp = (float*)(ws + 16777216); }
    else                             { NZg = 32; Gp = emb; }

    k_norm<<<NROW/4, 256, 0, stream>>>(X, nrm0, fpart);
    k_red<<<1, 256, 0, stream>>>(fpart, 2048, scal, linear, dirv, feat);
    k_gram<<<dim3(4,4,NZg), 256, 0, stream>>>(X, nrm0, scal, Gp, cpart);
    k_gred<<<257, 256, 0, stream>>>(Gp, cpart, G0, c0, NZg);
    k_apply<<<NROW/8, 256, 0, stream>>>(X, nrm0, scal, G0, c0, emb, nrm1, fpart1,
                                        cpart1, wpart1);
    k_sv<<<64, 256, 0, stream>>>(fpart1, scal, cpart1, wpart1, svec);
    k_uv<<<NROW/16, 256, 0, stream>>>(emb, nrm1, scal, fpart1, svec, u, vpart);
    k_vred<<<64, 256, 0, stream>>>(vpart, vvec);
    k_out<<<NROW/16, 256, 0, stream>>>(emb, nrm1, scal, fpart1, vvec, u, out);
}

// Round 8
// 135.989 us; speedup vs baseline: 1.2374x; 1.2374x over previous
//
#include <hip/hip_runtime.h>
#include <math.h>

constexpr int NROW = 8192;
constexpr int FD   = 256;

typedef unsigned short u16;
typedef __attribute__((ext_vector_type(8))) short short8;   // bf16 x8 (4 VGPR)
typedef __attribute__((ext_vector_type(4))) float f32x4;    // acc

// ws layout (bytes):
//   0        scal[8]
//   4096     nrm0[8192]        (32 KB)
//   36864    nrm1[8192]        (32 KB)
//   69632    fpart[2048]       (8 KB)
//   77824    fpart1[256]       (1 KB)
//   78848    c0[256]
//   79872    svec[256]
//   80896    vvec[256]
//   81920    u[8192]           (32 KB)
//   114688   cpart[128][256]   (128 KB)
//   245760   Gbf u16[256][256] (128 KB)
//   376832   cpart1[256][256]  (256 KB)
//   638976   wpart1[256][256]  (256 KB)
//   895232   vpart[512][256]   (512 KB)
//   2097152  Rbf u16[8192][256] (4 MB)  row-major bf16 of f0*X
//   6291456  Rt  u16[256][8192] (4 MB)  transposed bf16 of f0*X
//   10485760 Gp  f32[32][256][256] (8 MB)
//   18874368 emb f32[8192][256] (8 MB)

__device__ __forceinline__ float f_of(float nj, float A, float B, float AB) {
    float inner = AB * nj;
    return A - (inner <= 0.f ? inner : 0.f) * B;
}
__device__ __forceinline__ float wred(float s) {
    #pragma unroll
    for (int off = 32; off; off >>= 1) s += __shfl_xor(s, off);
    return s;
}
__device__ __forceinline__ float dot4(float4 a, float4 b) {
    return a.x*b.x + a.y*b.y + a.z*b.z + a.w*b.w;
}
__device__ __forceinline__ u16 f2bf(float x) {   // RNE fp32 -> bf16
    unsigned int u = __float_as_uint(x);
    u = (u + 0x7FFFu + ((u >> 16) & 1u)) >> 16;
    return (u16)u;
}

// one wave per row: nrm0[j] = ||row||^2 ; block partial -> fpart
__global__ void k_norm(const float* __restrict__ in, float* __restrict__ nrm,
                       float* __restrict__ fpart) {
    __shared__ float bs[4];
    int wave = threadIdx.x >> 6, lane = threadIdx.x & 63;
    int row = blockIdx.x * 4 + wave;
    const float4 v = *(const float4*)&in[(size_t)row * FD + lane * 4];
    float s = wred(dot4(v, v));
    if (lane == 0) { nrm[row] = s; bs[wave] = s; }
    __syncthreads();
    if (threadIdx.x == 0) fpart[blockIdx.x] = bs[0] + bs[1] + bs[2] + bs[3];
}

// 1 block: a,b dots; F2 = sum(fpart); scalars A,B,AB for depth 0
__global__ void k_red(const float* __restrict__ fpart, int n, float* __restrict__ scal,
                      const float* __restrict__ linear, const float* __restrict__ dirv,
                      const float* __restrict__ feat) {
    __shared__ float l[256];
    int tid = threadIdx.x;
    if (tid < 64) {
        for (int i = 0; i < 2; ++i) {
            float pa = 0.f, pb = 0.f;
            for (int k = tid; k < FD; k += 64) {
                float ll = linear[i*FD + k];
                pa += feat[i*FD + k] * ll;
                pb += dirv[i*FD + k] * ll;
            }
            pa = wred(pa); pb = wred(pb);
            if (tid == 0) { scal[i] = pa; scal[2 + i] = pb; }
        }
    }
    float s = 0.f;
    for (int j = tid; j < n; j += 256) s += fpart[j];
    l[tid] = s;
    __syncthreads();
    for (int off = 128; off; off >>= 1) {
        if (tid < off) l[tid] += l[tid + off];
        __syncthreads();
    }
    if (tid == 0) {
        float F2 = l[0];
        float a = scal[0], b = scal[2];
        float sb = (b > 0.f) ? 1.f : ((b < 0.f) ? -1.f : 0.f);
        float B = sb / sqrtf(F2);
        scal[4] = a; scal[5] = B; scal[6] = a * B; scal[7] = F2;
    }
}

// prep: R = f0*X in bf16, row-major (Rbf) + transposed (Rt); colsum partials cpart.
// 128 blocks x 64 rows.
__global__ void __launch_bounds__(256, 2)
k_prep(const float* __restrict__ X, const float* __restrict__ nrm0,
       const float* __restrict__ scal, u16* __restrict__ Rbf,
       u16* __restrict__ Rt, float* __restrict__ cpart) {
    __shared__ u16 Ltr[256][72];     // [col][row], stride 144 B (16B-aligned rows)
    __shared__ float cred[4][256];
    __shared__ float ff[64];
    const int tid = threadIdx.x;
    const int r0 = blockIdx.x * 64;
    if (tid < 64) ff[tid] = f_of(nrm0[r0 + tid], scal[4], scal[5], scal[6]);
    __syncthreads();
    const int cg = (tid & 63) * 4;   // 4 cols
    const int rg = tid >> 6;         // row group (16 rows)
    float4 csum = make_float4(0.f, 0.f, 0.f, 0.f);
    for (int i = 0; i < 16; ++i) {
        int row = rg * 16 + i;
        float4 v = *(const float4*)&X[(size_t)(r0 + row) * FD + cg];
        float f = ff[row];
        v.x *= f; v.y *= f; v.z *= f; v.w *= f;
        csum.x += v.x; csum.y += v.y; csum.z += v.z; csum.w += v.w;
        u16 h0 = f2bf(v.x), h1 = f2bf(v.y), h2 = f2bf(v.z), h3 = f2bf(v.w);
        u16* rb = Rbf + (size_t)(r0 + row) * FD + cg;
        rb[0] = h0; rb[1] = h1; rb[2] = h2; rb[3] = h3;
        Ltr[cg + 0][row] = h0; Ltr[cg + 1][row] = h1;
        Ltr[cg + 2][row] = h2; Ltr[cg + 3][row] = h3;
    }
    *(float4*)&cred[rg][cg] = csum;
    __syncthreads();
    cpart[(size_t)blockIdx.x * FD + tid] =
        cred[0][tid] + cred[1][tid] + cred[2][tid] + cred[3][tid];
    // Rt write: c = Rt row (a column of R); 4 threads cover the 64-row chunk
    #pragma unroll
    for (int it = 0; it < 4; ++it) {
        int c = (tid >> 2) + it * 64;
        int chunk = (tid & 3) * 16;
        uint4 u0 = *(const uint4*)&Ltr[c][chunk];
        uint4 u1 = *(const uint4*)&Ltr[c][chunk + 8];
        u16* rt = Rt + (size_t)c * NROW + r0 + chunk;
        *(uint4*)(rt)     = u0;
        *(uint4*)(rt + 8) = u1;
    }
}

// Gram partials via MFMA: Gp[z][m][n] = sum_{k in z-chunk} Rt[m][k]*Rt[n][k].
// grid (4,4,32); block = 4 waves, each a 32x32 quadrant of the 64x64 tile.
__global__ void __launch_bounds__(256, 2)
k_gram(const u16* __restrict__ Rt, float* __restrict__ Gp) {
    const int bi = blockIdx.x, bj = blockIdx.y, z = blockIdx.z;
    const int tid = threadIdx.x, w = tid >> 6, lane = tid & 63;
    const int l15 = lane & 15, quad = lane >> 4;
    const int m0 = bi * 64 + (w & 1) * 32;
    const int n0 = bj * 64 + (w >> 1) * 32;
    const size_t kbase = (size_t)z * 256 + quad * 8;
    const u16* am0 = Rt + (size_t)(m0 + l15) * NROW + kbase;
    const u16* am1 = am0 + (size_t)16 * NROW;
    const u16* bn0 = Rt + (size_t)(n0 + l15) * NROW + kbase;
    const u16* bn1 = bn0 + (size_t)16 * NROW;
    f32x4 acc[2][2] = {};
    #pragma unroll
    for (int s = 0; s < 8; ++s) {
        int ko = s * 32;
        short8 a0 = *(const short8*)(am0 + ko);
        short8 a1 = *(const short8*)(am1 + ko);
        short8 b0 = *(const short8*)(bn0 + ko);
        short8 b1 = *(const short8*)(bn1 + ko);
        acc[0][0] = __builtin_amdgcn_mfma_f32_16x16x32_bf16(a0, b0, acc[0][0], 0, 0, 0);
        acc[0][1] = __builtin_amdgcn_mfma_f32_16x16x32_bf16(a0, b1, acc[0][1], 0, 0, 0);
        acc[1][0] = __builtin_amdgcn_mfma_f32_16x16x32_bf16(a1, b0, acc[1][0], 0, 0, 0);
        acc[1][1] = __builtin_amdgcn_mfma_f32_16x16x32_bf16(a1, b1, acc[1][1], 0, 0, 0);
    }
    float* gz = Gp + (size_t)z * (FD * FD);
    #pragma unroll
    for (int mi = 0; mi < 2; ++mi)
        #pragma unroll
        for (int ni = 0; ni < 2; ++ni)
            #pragma unroll
            for (int r = 0; r < 4; ++r)
                gz[(size_t)(m0 + mi*16 + quad*4 + r) * FD + n0 + ni*16 + l15] =
                    acc[mi][ni][r];
}

// blocks 0..255: Gbf = bf16(sum_z Gp) ; block 256: c0 = sum_b cpart
__global__ void k_gred(const float* __restrict__ Gp, const float* __restrict__ cpart,
                       u16* __restrict__ Gbf, float* __restrict__ c0) {
    int tid = threadIdx.x;
    if (blockIdx.x < 256) {
        size_t e0 = (size_t)blockIdx.x * 256 + tid;
        float s = 0.f;
        #pragma unroll 8
        for (int z = 0; z < 32; ++z) s += Gp[(size_t)z * (FD * FD) + e0];
        Gbf[e0] = f2bf(s);
    } else {
        float s = 0.f;
        #pragma unroll 8
        for (int b = 0; b < 128; ++b) s += cpart[(size_t)b * FD + tid];
        c0[tid] = s;
    }
}

// apply via MFMA: Sraw = R @ G (G symmetric -> b_frag from row-major Gbf).
// 256 blocks x 32 rows; wave w owns cols w*64..+64 (2x4 tiles of 16x16x32).
// fp32 epilogue: emb' = r + (Sraw - (r.c0) r)/N, emits nrm1/fpart1/cpart1/wpart1.
__global__ void __launch_bounds__(256, 2)
k_apply(const float* __restrict__ X, const u16* __restrict__ Rbf,
        const u16* __restrict__ Gbf, const float* __restrict__ nrm0,
        const float* __restrict__ scal, const float* __restrict__ c0,
        float* __restrict__ emb, float* __restrict__ nrm1,
        float* __restrict__ fpart1, float* __restrict__ cpart1,
        float* __restrict__ wpart1) {
    __shared__ float Sl[32][260];
    __shared__ float u0s[32], ffs[32], nrs[32];
    __shared__ float nw[32][4];
    const int tid = threadIdx.x, w = tid >> 6, lane = tid & 63;
    const int l15 = lane & 15, quad = lane >> 4;
    const int r0 = blockIdx.x * 32;
    const float A = scal[4], B = scal[5], AB = scal[6];

    if (tid < 32) ffs[tid] = f_of(nrm0[r0 + tid], A, B, AB);
    __syncthreads();
    // u0[row] = f0_row * (X_row . c0): wave w does rows w*8..w*8+8
    #pragma unroll
    for (int jj = 0; jj < 8; ++jj) {
        int row = w * 8 + jj;
        float4 xv = *(const float4*)&X[(size_t)(r0 + row) * FD + lane * 4];
        float4 cv = *(const float4*)&c0[lane * 4];
        float t = wred(dot4(xv, cv));
        if (lane == 0) u0s[row] = ffs[row] * t;
    }

    // MFMA K-loop
    const u16* ap0 = Rbf + (size_t)(r0 + l15) * FD + quad * 8;
    const u16* ap1 = ap0 + (size_t)16 * FD;
    const int n0w = w * 64;
    const u16* bp = Gbf + (size_t)(n0w + l15) * FD + quad * 8;
    f32x4 acc[2][4] = {};
    #pragma unroll
    for (int s = 0; s < 8; ++s) {
        int ko = s * 32;
        short8 a0 = *(const short8*)(ap0 + ko);
        short8 a1 = *(const short8*)(ap1 + ko);
        short8 b0 = *(const short8*)(bp + ko);
        short8 b1 = *(const short8*)(bp + 16 * FD + ko);
        short8 b2 = *(const short8*)(bp + 32 * FD + ko);
        short8 b3 = *(const short8*)(bp + 48 * FD + ko);
        acc[0][0] = __builtin_amdgcn_mfma_f32_16x16x32_bf16(a0, b0, acc[0][0], 0, 0, 0);
        acc[0][1] = __builtin_amdgcn_mfma_f32_16x16x32_bf16(a0, b1, acc[0][1], 0, 0, 0);
        acc[0][2] = __builtin_amdgcn_mfma_f32_16x16x32_bf16(a0, b2, acc[0][2], 0, 0, 0);
        acc[0][3] = __builtin_amdgcn_mfma_f32_16x16x32_bf16(a0, b3, acc[0][3], 0, 0, 0);
        acc[1][0] = __builtin_amdgcn_mfma_f32_16x16x32_bf16(a1, b0, acc[1][0], 0, 0, 0);
        acc[1][1] = __builtin_amdgcn_mfma_f32_16x16x32_bf16(a1, b1, acc[1][1], 0, 0, 0);
        acc[1][2] = __builtin_amdgcn_mfma_f32_16x16x32_bf16(a1, b2, acc[1][2], 0, 0, 0);
        acc[1][3] = __builtin_amdgcn_mfma_f32_16x16x32_bf16(a1, b3, acc[1][3], 0, 0, 0);
    }
    // bridge: MFMA C/D layout -> LDS (row = mi*16+quad*4+r, col = n0w+ni*16+l15)
    #pragma unroll
    for (int mi = 0; mi < 2; ++mi)
        #pragma unroll
        for (int ni = 0; ni < 4; ++ni)
            #pragma unroll
            for (int r = 0; r < 4; ++r)
                Sl[mi*16 + quad*4 + r][n0w + ni*16 + l15] = acc[mi][ni][r];
    __syncthreads();

    // fp32 epilogue: thread = column tid
    const float invN = 1.0f / NROW;
    float er[32];
    float csum = 0.f;
    #pragma unroll
    for (int j = 0; j < 32; ++j) {
        float x = X[(size_t)(r0 + j) * FD + tid];
        float rv = ffs[j] * x;
        float e = rv + (Sl[j][tid] - u0s[j] * rv) * invN;
        emb[(size_t)(r0 + j) * FD + tid] = e;
        er[j] = e;
        csum += e;
        float s2 = wred(e * e);
        if (lane == 0) nw[j][w] = s2;
    }
    __syncthreads();
    if (tid < 32) {
        float nn = nw[tid][0] + nw[tid][1] + nw[tid][2] + nw[tid][3];
        nrm1[r0 + tid] = nn;
        nrs[tid] = nn;
    }
    __syncthreads();
    float wsum = 0.f;
    #pragma unroll
    for (int j = 0; j < 32; ++j) wsum += nrs[j] * er[j];
    cpart1[(size_t)blockIdx.x * FD + tid] = csum;
    wpart1[(size_t)blockIdx.x * FD + tid] = wsum;
    if (tid == 0) {
        float fp = 0.f;
        #pragma unroll
        for (int j = 0; j < 32; ++j) fp += nrs[j];
        fpart1[blockIdx.x] = fp;
    }
}

// depth-1 scalars from fpart1[256]
__device__ __forceinline__ void red1_scal(const float* fpart1, const float* scal,
                                          float* l, float& A, float& B, float& AB,
                                          float& kap) {
    int tid = threadIdx.x;
    l[tid] = fpart1[tid];
    __syncthreads();
    for (int off = 128; off; off >>= 1) {
        if (tid < off) l[tid] += l[tid + off];
        __syncthreads();
    }
    float F2 = l[0];
    float a = scal[1], b = scal[3];
    float sb = (b > 0.f) ? 1.f : ((b < 0.f) ? -1.f : 0.f);
    B = sb / sqrtf(F2);
    A = a; AB = a * B;
    kap = (AB <= 0.f) ? AB * B : 0.f;
    __syncthreads();
}

// svec[col] = A1 * sum_b cpart1[b][col] - kappa * sum_b wpart1[b][col]
__global__ void k_sv(const float* __restrict__ fpart1, const float* __restrict__ scal,
                     const float* __restrict__ cpart1, const float* __restrict__ wpart1,
                     float* __restrict__ svec) {
    __shared__ float l[256];
    float A1, B1, AB1, kap;
    red1_scal(fpart1, scal, l, A1, B1, AB1, kap);
    int tid = threadIdx.x;
    int col = blockIdx.x * 4 + (tid >> 6);
    int lane = tid & 63;
    float cs = 0.f, wsm = 0.f;
    #pragma unroll
    for (int b = lane; b < 256; b += 64) {
        cs  += cpart1[(size_t)b * FD + col];
        wsm += wpart1[(size_t)b * FD + col];
    }
    #pragma unroll
    for (int off = 32; off; off >>= 1) {
        cs  += __shfl_down(cs, off);
        wsm += __shfl_down(wsm, off);
    }
    if (lane == 0) svec[col] = A1 * cs - kap * wsm;
}

// u[row] = f1 (emb'_row . s) ; vpart[bid][col] = sum_j (u_j f1_j) emb'[j][col]
__global__ void k_uv(const float* __restrict__ emb, const float* __restrict__ nrm1,
                     const float* __restrict__ scal, const float* __restrict__ fpart1,
                     const float* __restrict__ svec, float* __restrict__ u,
                     float* __restrict__ vpart) {
    __shared__ float l[256];
    __shared__ float ssh[FD];
    __shared__ float uf[16];
    float A, B, AB, kap;
    red1_scal(fpart1, scal, l, A, B, AB, kap);
    int tid = threadIdx.x;
    int r0 = blockIdx.x * 16;
    ssh[tid] = svec[tid];
    __syncthreads();
    const int wave = tid >> 6, lane = tid & 63;
    float4 sv = *(const float4*)&ssh[lane*4];
    #pragma unroll
    for (int jj = 0; jj < 4; ++jj) {
        int row = r0 + wave * 4 + jj;
        float4 ev = *(const float4*)&emb[(size_t)row * FD + lane*4];
        float s = wred(dot4(ev, sv));
        if (lane == 0) {
            float f = A - kap * nrm1[row];
            float uj = f * s;
            u[row] = uj;
            uf[wave*4 + jj] = uj * f;
        }
    }
    __syncthreads();
    float vp = 0.f;
    #pragma unroll
    for (int j = 0; j < 16; ++j)
        vp += uf[j] * emb[(size_t)(r0 + j) * FD + tid];
    vpart[(size_t)blockIdx.x * FD + tid] = vp;
}

// reduce vpart[512][256] -> vvec[256]
__global__ void k_vred(const float* __restrict__ part, float* __restrict__ vec) {
    int tid = threadIdx.x;
    int col = blockIdx.x * 4 + (tid >> 6);
    int lane = tid & 63;
    float s = 0.f;
    #pragma unroll
    for (int b = 0; b < 8; ++b) s += part[(size_t)(b * 64 + lane) * FD + col];
    #pragma unroll
    for (int off = 32; off; off >>= 1) s += __shfl_down(s, off);
    if (lane == 0) vec[col] = s;
}

// out[row] = (u + (f1*(emb'_row . v) - u^2)/N)/N
__global__ void k_out(const float* __restrict__ emb, const float* __restrict__ nrm1,
                      const float* __restrict__ scal, const float* __restrict__ fpart1,
                      const float* __restrict__ vvec, const float* __restrict__ u,
                      float* __restrict__ out) {
    __shared__ float l[256];
    __shared__ float vsh[FD];
    float A, B, AB, kap;
    red1_scal(fpart1, scal, l, A, B, AB, kap);
    int tid = threadIdx.x;
    int r0 = blockIdx.x * 16;
    vsh[tid] = vvec[tid];
    __syncthreads();
    const int wave = tid >> 6, lane = tid & 63;
    const float invN = 1.0f / NROW;
    float4 vv = *(const float4*)&vsh[lane*4];
    #pragma unroll
    for (int jj = 0; jj < 4; ++jj) {
        int row = r0 + wave * 4 + jj;
        float4 ev = *(const float4*)&emb[(size_t)row * FD + lane*4];
        float s = wred(dot4(ev, vv));
        if (lane == 0 && row < NROW - 1) {
            float f = A - kap * nrm1[row];
            float uj = u[row];
            out[row] = (uj + (f * s - uj * uj) * invN) * invN;
        }
    }
}

extern "C" void kernel_launch(void* const* d_in, const int* in_sizes, int n_in,
                              void* d_out, int out_size, void* d_ws, size_t ws_size,
                              hipStream_t stream) {
    const float* X      = (const float*)d_in[0];
    // d_in[1] = coefs (unused by the reference forward)
    const float* linear = (const float*)d_in[2];
    const float* dirv   = (const float*)d_in[3];
    const float* feat   = (const float*)d_in[4];
    float* out = (float*)d_out;

    char* ws = (char*)d_ws;
    float* scal   = (float*)(ws + 0);
    float* nrm0   = (float*)(ws + 4096);
    float* nrm1   = (float*)(ws + 36864);
    float* fpart  = (float*)(ws + 69632);
    float* fpart1 = (float*)(ws + 77824);
    float* c0     = (float*)(ws + 78848);
    float* svec   = (float*)(ws + 79872);
    float* vvec   = (float*)(ws + 80896);
    float* u      = (float*)(ws + 81920);
    float* cpart  = (float*)(ws + 114688);
    u16*   Gbf    = (u16*)  (ws + 245760);
    float* cpart1 = (float*)(ws + 376832);
    float* wpart1 = (float*)(ws + 638976);
    float* vpart  = (float*)(ws + 895232);
    u16*   Rbf    = (u16*)  (ws + 2097152);
    u16*   Rt     = (u16*)  (ws + 6291456);
    float* Gp     = (float*)(ws + 10485760);
    float* emb    = (float*)(ws + 18874368);

    k_norm<<<NROW/4, 256, 0, stream>>>(X, nrm0, fpart);
    k_red<<<1, 256, 0, stream>>>(fpart, 2048, scal, linear, dirv, feat);
    k_prep<<<128, 256, 0, stream>>>(X, nrm0, scal, Rbf, Rt, cpart);
    k_gram<<<dim3(4,4,32), 256, 0, stream>>>(Rt, Gp);
    k_gred<<<257, 256, 0, stream>>>(Gp, cpart, Gbf, c0);
    k_apply<<<256, 256, 0, stream>>>(X, Rbf, Gbf, nrm0, scal, c0, emb, nrm1,
                                     fpart1, cpart1, wpart1);
    k_sv<<<64, 256, 0, stream>>>(fpart1, scal, cpart1, wpart1, svec);
    k_uv<<<NROW/16, 256, 0, stream>>>(emb, nrm1, scal, fpart1, svec, u, vpart);
    k_vred<<<64, 256, 0, stream>>>(vpart, vvec);
    k_out<<<NROW/16, 256, 0, stream>>>(emb, nrm1, scal, fpart1, vvec, u, out);
}

// Round 9
// 127.129 us; speedup vs baseline: 1.3237x; 1.0697x over previous
//
#include <hip/hip_runtime.h>
#include <math.h>

constexpr int NROW = 8192;
constexpr int FD   = 256;
constexpr int NZ   = 16;

typedef unsigned short u16;
typedef __attribute__((ext_vector_type(8))) short short8;   // bf16 x8 (4 VGPR)
typedef __attribute__((ext_vector_type(4))) float f32x4;    // acc

// ws layout (bytes):
//   0        scal[8]
//   4096     nrm0[8192]        (32 KB)
//   36864    nrm1[8192]        (32 KB)
//   69632    fpart[2048]       (8 KB)
//   77824    fpart1[256]
//   78848    c0[256]
//   79872    svec[256]
//   80896    vvec[256]
//   81920    u[8192]           (32 KB)
//   114688   f0[8192]          (32 KB)
//   147456   cpart[128][256]   (128 KB)
//   278528   Gbf u16[256][256] (128 KB)
//   409600   cpart1[256][256]  (256 KB)
//   671744   wpart1[256][256]  (256 KB)
//   933888   vpart[512][256]   (512 KB)
//   2097152  Rbf u16[8192][256] (4 MB)
//   6291456  Rt  u16[256][8192] (4 MB)
//   10485760 Gp  f32[16][256][256] (4 MB)
//   18874368 emb f32[8192][256] (8 MB)

__device__ __forceinline__ float f_of(float nj, float A, float B, float AB) {
    float inner = AB * nj;
    return A - (inner <= 0.f ? inner : 0.f) * B;
}
__device__ __forceinline__ float wred(float s) {
    #pragma unroll
    for (int off = 32; off; off >>= 1) s += __shfl_xor(s, off);
    return s;
}
__device__ __forceinline__ float dot4(float4 a, float4 b) {
    return a.x*b.x + a.y*b.y + a.z*b.z + a.w*b.w;
}
__device__ __forceinline__ u16 f2bf(float x) {   // RNE fp32 -> bf16
    unsigned int u = __float_as_uint(x);
    u = (u + 0x7FFFu + ((u >> 16) & 1u)) >> 16;
    return (u16)u;
}

// one wave per row: nrm0[j] = ||row||^2 ; block partial -> fpart
__global__ void k_norm(const float* __restrict__ in, float* __restrict__ nrm,
                       float* __restrict__ fpart) {
    __shared__ float bs[4];
    int wave = threadIdx.x >> 6, lane = threadIdx.x & 63;
    int row = blockIdx.x * 4 + wave;
    const float4 v = *(const float4*)&in[(size_t)row * FD + lane * 4];
    float s = wred(dot4(v, v));
    if (lane == 0) { nrm[row] = s; bs[wave] = s; }
    __syncthreads();
    if (threadIdx.x == 0) fpart[blockIdx.x] = bs[0] + bs[1] + bs[2] + bs[3];
}

// prep (folds old k_red): per-block redundant scalar derivation, then
// R = f0*X in bf16 row-major (Rbf) + transposed (Rt) + colsum partials + f0 array.
// 128 blocks x 64 rows.
__global__ void __launch_bounds__(256, 2)
k_prep(const float* __restrict__ X, const float* __restrict__ nrm0,
       const float* __restrict__ fpart, const float* __restrict__ linear,
       const float* __restrict__ dirv, const float* __restrict__ feat,
       float* __restrict__ scal, float* __restrict__ f0,
       u16* __restrict__ Rbf, u16* __restrict__ Rt, float* __restrict__ cpart) {
    __shared__ u16 T[64][264];       // row-major bf16 tile (stride 264: 16B-mult)
    __shared__ float cred[4][256];
    __shared__ float l[256];
    __shared__ float ff[64];
    __shared__ float sdot[4];
    const int tid = threadIdx.x;
    const int r0 = blockIdx.x * 64;

    // a,b dots (wave 0)
    if (tid < 64) {
        for (int i = 0; i < 2; ++i) {
            float pa = 0.f, pb = 0.f;
            for (int k = tid; k < FD; k += 64) {
                float ll = linear[i*FD + k];
                pa += feat[i*FD + k] * ll;
                pb += dirv[i*FD + k] * ll;
            }
            pa = wred(pa); pb = wred(pb);
            if (tid == 0) { sdot[i] = pa; sdot[2 + i] = pb; }
        }
    }
    // F2 reduce over fpart[2048]
    float s = 0.f;
    #pragma unroll
    for (int k = 0; k < 8; ++k) s += fpart[tid + k * 256];
    l[tid] = s;
    __syncthreads();
    for (int off = 128; off; off >>= 1) {
        if (tid < off) l[tid] += l[tid + off];
        __syncthreads();
    }
    const float F2 = l[0];
    const float a = sdot[0], b = sdot[2];
    const float sb = (b > 0.f) ? 1.f : ((b < 0.f) ? -1.f : 0.f);
    const float B = sb / sqrtf(F2);
    const float A = a, AB = a * B;
    if (blockIdx.x == 0 && tid == 0) {
        scal[0] = sdot[0]; scal[1] = sdot[1]; scal[2] = sdot[2]; scal[3] = sdot[3];
        scal[4] = A; scal[5] = B; scal[6] = AB; scal[7] = F2;
    }
    if (tid < 64) {
        float f = f_of(nrm0[r0 + tid], A, B, AB);
        ff[tid] = f;
        f0[r0 + tid] = f;
    }
    __syncthreads();

    // scale, bf16-convert, store Rbf + LDS tile (conflict-free packed writes)
    const int cg = (tid & 63) * 4;   // 4 cols
    const int rg = tid >> 6;         // row group (16 rows)
    float4 csum = make_float4(0.f, 0.f, 0.f, 0.f);
    for (int i = 0; i < 16; ++i) {
        int row = rg * 16 + i;
        float4 v = *(const float4*)&X[(size_t)(r0 + row) * FD + cg];
        float f = ff[row];
        v.x *= f; v.y *= f; v.z *= f; v.w *= f;
        csum.x += v.x; csum.y += v.y; csum.z += v.z; csum.w += v.w;
        unsigned lo = (unsigned)f2bf(v.x) | ((unsigned)f2bf(v.y) << 16);
        unsigned hi = (unsigned)f2bf(v.z) | ((unsigned)f2bf(v.w) << 16);
        uint2 pk = make_uint2(lo, hi);
        *(uint2*)&Rbf[(size_t)(r0 + row) * FD + cg] = pk;
        *(uint2*)&T[row][cg] = pk;
    }
    *(float4*)&cred[rg][cg] = csum;
    __syncthreads();
    cpart[(size_t)blockIdx.x * FD + tid] =
        cred[0][tid] + cred[1][tid] + cred[2][tid] + cred[3][tid];

    // Rt: thread = column c; scalar column gather (conflict-free), 16B stores
    const int c = tid;
    #pragma unroll
    for (int ch = 0; ch < 8; ++ch) {
        unsigned w0 = (unsigned)T[ch*8+0][c] | ((unsigned)T[ch*8+1][c] << 16);
        unsigned w1 = (unsigned)T[ch*8+2][c] | ((unsigned)T[ch*8+3][c] << 16);
        unsigned w2 = (unsigned)T[ch*8+4][c] | ((unsigned)T[ch*8+5][c] << 16);
        unsigned w3 = (unsigned)T[ch*8+6][c] | ((unsigned)T[ch*8+7][c] << 16);
        uint4 o = make_uint4(w0, w1, w2, w3);
        *(uint4*)&Rt[(size_t)c * NROW + r0 + ch * 8] = o;
    }
}

// Gram partials via MFMA: Gp[z][m][n] = sum_{k in z-chunk(512)} Rt[m][k]*Rt[n][k].
// grid (4,4,16); block = 4 waves, each a 32x32 quadrant of the 64x64 tile.
__global__ void __launch_bounds__(256, 2)
k_gram(const u16* __restrict__ Rt, float* __restrict__ Gp) {
    const int bi = blockIdx.x, bj = blockIdx.y, z = blockIdx.z;
    const int tid = threadIdx.x, w = tid >> 6, lane = tid & 63;
    const int l15 = lane & 15, quad = lane >> 4;
    const int m0 = bi * 64 + (w & 1) * 32;
    const int n0 = bj * 64 + (w >> 1) * 32;
    const size_t kbase = (size_t)z * 512 + quad * 8;
    const u16* am0 = Rt + (size_t)(m0 + l15) * NROW + kbase;
    const u16* am1 = am0 + (size_t)16 * NROW;
    const u16* bn0 = Rt + (size_t)(n0 + l15) * NROW + kbase;
    const u16* bn1 = bn0 + (size_t)16 * NROW;
    f32x4 acc[2][2] = {};
    #pragma unroll
    for (int s = 0; s < 16; ++s) {
        int ko = s * 32;
        short8 a0 = *(const short8*)(am0 + ko);
        short8 a1 = *(const short8*)(am1 + ko);
        short8 b0 = *(const short8*)(bn0 + ko);
        short8 b1 = *(const short8*)(bn1 + ko);
        acc[0][0] = __builtin_amdgcn_mfma_f32_16x16x32_bf16(a0, b0, acc[0][0], 0, 0, 0);
        acc[0][1] = __builtin_amdgcn_mfma_f32_16x16x32_bf16(a0, b1, acc[0][1], 0, 0, 0);
        acc[1][0] = __builtin_amdgcn_mfma_f32_16x16x32_bf16(a1, b0, acc[1][0], 0, 0, 0);
        acc[1][1] = __builtin_amdgcn_mfma_f32_16x16x32_bf16(a1, b1, acc[1][1], 0, 0, 0);
    }
    float* gz = Gp + (size_t)z * (FD * FD);
    #pragma unroll
    for (int mi = 0; mi < 2; ++mi)
        #pragma unroll
        for (int ni = 0; ni < 2; ++ni)
            #pragma unroll
            for (int r = 0; r < 4; ++r)
                gz[(size_t)(m0 + mi*16 + quad*4 + r) * FD + n0 + ni*16 + l15] =
                    acc[mi][ni][r];
}

// blocks 0..255: Gbf = bf16(sum_z Gp) ; block 256: c0 = sum_b cpart
__global__ void k_gred(const float* __restrict__ Gp, const float* __restrict__ cpart,
                       u16* __restrict__ Gbf, float* __restrict__ c0) {
    int tid = threadIdx.x;
    if (blockIdx.x < 256) {
        size_t e0 = (size_t)blockIdx.x * 256 + tid;
        float s = 0.f;
        #pragma unroll
        for (int z = 0; z < NZ; ++z) s += Gp[(size_t)z * (FD * FD) + e0];
        Gbf[e0] = f2bf(s);
    } else {
        float s = 0.f;
        #pragma unroll 8
        for (int b = 0; b < 128; ++b) s += cpart[(size_t)b * FD + tid];
        c0[tid] = s;
    }
}

// apply via MFMA: Sraw = R @ G (G symmetric -> b_frag from row-major Gbf).
// 256 blocks x 32 rows. fp32 epilogue with LDS-based row-norm reduction.
__global__ void __launch_bounds__(256, 2)
k_apply(const float* __restrict__ X, const u16* __restrict__ Rbf,
        const u16* __restrict__ Gbf, const float* __restrict__ f0,
        const float* __restrict__ c0, float* __restrict__ emb,
        float* __restrict__ nrm1, float* __restrict__ fpart1,
        float* __restrict__ cpart1, float* __restrict__ wpart1) {
    __shared__ float Sl[32][260];
    __shared__ float u0s[32], ffs[32], nrs[32];
    __shared__ float nw8[32][8];
    const int tid = threadIdx.x, w = tid >> 6, lane = tid & 63;
    const int l15 = lane & 15, quad = lane >> 4;
    const int r0 = blockIdx.x * 32;

    if (tid < 32) ffs[tid] = f0[r0 + tid];
    __syncthreads();
    // u0[row] = f0_row * (X_row . c0): wave w does rows w*8..w*8+8
    #pragma unroll
    for (int jj = 0; jj < 8; ++jj) {
        int row = w * 8 + jj;
        float4 xv = *(const float4*)&X[(size_t)(r0 + row) * FD + lane * 4];
        float4 cv = *(const float4*)&c0[lane * 4];
        float t = wred(dot4(xv, cv));
        if (lane == 0) u0s[row] = ffs[row] * t;
    }

    // MFMA K-loop
    const u16* ap0 = Rbf + (size_t)(r0 + l15) * FD + quad * 8;
    const u16* ap1 = ap0 + (size_t)16 * FD;
    const int n0w = w * 64;
    const u16* bp = Gbf + (size_t)(n0w + l15) * FD + quad * 8;
    f32x4 acc[2][4] = {};
    #pragma unroll
    for (int s = 0; s < 8; ++s) {
        int ko = s * 32;
        short8 a0 = *(const short8*)(ap0 + ko);
        short8 a1 = *(const short8*)(ap1 + ko);
        short8 b0 = *(const short8*)(bp + ko);
        short8 b1 = *(const short8*)(bp + 16 * FD + ko);
        short8 b2 = *(const short8*)(bp + 32 * FD + ko);
        short8 b3 = *(const short8*)(bp + 48 * FD + ko);
        acc[0][0] = __builtin_amdgcn_mfma_f32_16x16x32_bf16(a0, b0, acc[0][0], 0, 0, 0);
        acc[0][1] = __builtin_amdgcn_mfma_f32_16x16x32_bf16(a0, b1, acc[0][1], 0, 0, 0);
        acc[0][2] = __builtin_amdgcn_mfma_f32_16x16x32_bf16(a0, b2, acc[0][2], 0, 0, 0);
        acc[0][3] = __builtin_amdgcn_mfma_f32_16x16x32_bf16(a0, b3, acc[0][3], 0, 0, 0);
        acc[1][0] = __builtin_amdgcn_mfma_f32_16x16x32_bf16(a1, b0, acc[1][0], 0, 0, 0);
        acc[1][1] = __builtin_amdgcn_mfma_f32_16x16x32_bf16(a1, b1, acc[1][1], 0, 0, 0);
        acc[1][2] = __builtin_amdgcn_mfma_f32_16x16x32_bf16(a1, b2, acc[1][2], 0, 0, 0);
        acc[1][3] = __builtin_amdgcn_mfma_f32_16x16x32_bf16(a1, b3, acc[1][3], 0, 0, 0);
    }
    // bridge: MFMA C/D layout -> LDS (row = mi*16+quad*4+r, col = n0w+ni*16+l15)
    #pragma unroll
    for (int mi = 0; mi < 2; ++mi)
        #pragma unroll
        for (int ni = 0; ni < 4; ++ni)
            #pragma unroll
            for (int r = 0; r < 4; ++r)
                Sl[mi*16 + quad*4 + r][n0w + ni*16 + l15] = acc[mi][ni][r];
    __syncthreads();

    // fp32 epilogue: thread = column tid
    const float invN = 1.0f / NROW;
    float er[32];
    float csum = 0.f;
    #pragma unroll
    for (int j = 0; j < 32; ++j) {
        float x = X[(size_t)(r0 + j) * FD + tid];
        float rv = ffs[j] * x;
        float e = rv + (Sl[j][tid] - u0s[j] * rv) * invN;
        emb[(size_t)(r0 + j) * FD + tid] = e;
        er[j] = e;
        csum += e;
        Sl[j][tid] = e * e;
    }
    __syncthreads();
    {   // row-norm reduce via LDS: thread handles row tid&31, col-chunk tid>>5
        int row = tid & 31, q = tid >> 5;
        float pn = 0.f;
        #pragma unroll
        for (int i = 0; i < 32; ++i) pn += Sl[row][q * 32 + i];
        nw8[row][q] = pn;
    }
    __syncthreads();
    if (tid < 32) {
        float nn = 0.f;
        #pragma unroll
        for (int q = 0; q < 8; ++q) nn += nw8[tid][q];
        nrm1[r0 + tid] = nn;
        nrs[tid] = nn;
    }
    __syncthreads();
    float wsum = 0.f;
    #pragma unroll
    for (int j = 0; j < 32; ++j) wsum += nrs[j] * er[j];
    cpart1[(size_t)blockIdx.x * FD + tid] = csum;
    wpart1[(size_t)blockIdx.x * FD + tid] = wsum;
    if (tid == 0) {
        float fp = 0.f;
        #pragma unroll
        for (int j = 0; j < 32; ++j) fp += nrs[j];
        fpart1[blockIdx.x] = fp;
    }
}

// depth-1 scalars from fpart1[256]
__device__ __forceinline__ void red1_scal(const float* fpart1, const float* scal,
                                          float* l, float& A, float& B, float& AB,
                                          float& kap) {
    int tid = threadIdx.x;
    l[tid] = fpart1[tid];
    __syncthreads();
    for (int off = 128; off; off >>= 1) {
        if (tid < off) l[tid] += l[tid + off];
        __syncthreads();
    }
    float F2 = l[0];
    float a = scal[1], b = scal[3];
    float sb = (b > 0.f) ? 1.f : ((b < 0.f) ? -1.f : 0.f);
    B = sb / sqrtf(F2);
    A = a; AB = a * B;
    kap = (AB <= 0.f) ? AB * B : 0.f;
    __syncthreads();
}

// svec[col] = A1 * sum_b cpart1[b][col] - kappa * sum_b wpart1[b][col]
__global__ void k_sv(const float* __restrict__ fpart1, const float* __restrict__ scal,
                     const float* __restrict__ cpart1, const float* __restrict__ wpart1,
                     float* __restrict__ svec) {
    __shared__ float l[256];
    float A1, B1, AB1, kap;
    red1_scal(fpart1, scal, l, A1, B1, AB1, kap);
    int tid = threadIdx.x;
    int col = blockIdx.x * 4 + (tid >> 6);
    int lane = tid & 63;
    float cs = 0.f, wsm = 0.f;
    #pragma unroll
    for (int b = lane; b < 256; b += 64) {
        cs  += cpart1[(size_t)b * FD + col];
        wsm += wpart1[(size_t)b * FD + col];
    }
    #pragma unroll
    for (int off = 32; off; off >>= 1) {
        cs  += __shfl_down(cs, off);
        wsm += __shfl_down(wsm, off);
    }
    if (lane == 0) svec[col] = A1 * cs - kap * wsm;
}

// u[row] = f1 (emb'_row . s) ; vpart[bid][col] = sum_j (u_j f1_j) emb'[j][col]
__global__ void k_uv(const float* __restrict__ emb, const float* __restrict__ nrm1,
                     const float* __restrict__ scal, const float* __restrict__ fpart1,
                     const float* __restrict__ svec, float* __restrict__ u,
                     float* __restrict__ vpart) {
    __shared__ float l[256];
    __shared__ float ssh[FD];
    __shared__ float uf[16];
    float A, B, AB, kap;
    red1_scal(fpart1, scal, l, A, B, AB, kap);
    int tid = threadIdx.x;
    int r0 = blockIdx.x * 16;
    ssh[tid] = svec[tid];
    __syncthreads();
    const int wave = tid >> 6, lane = tid & 63;
    float4 sv = *(const float4*)&ssh[lane*4];
    #pragma unroll
    for (int jj = 0; jj < 4; ++jj) {
        int row = r0 + wave * 4 + jj;
        float4 ev = *(const float4*)&emb[(size_t)row * FD + lane*4];
        float s = wred(dot4(ev, sv));
        if (lane == 0) {
            float f = A - kap * nrm1[row];
            float uj = f * s;
            u[row] = uj;
            uf[wave*4 + jj] = uj * f;
        }
    }
    __syncthreads();
    float vp = 0.f;
    #pragma unroll
    for (int j = 0; j < 16; ++j)
        vp += uf[j] * emb[(size_t)(r0 + j) * FD + tid];
    vpart[(size_t)blockIdx.x * FD + tid] = vp;
}

// reduce vpart[512][256] -> vvec[256]
__global__ void k_vred(const float* __restrict__ part, float* __restrict__ vec) {
    int tid = threadIdx.x;
    int col = blockIdx.x * 4 + (tid >> 6);
    int lane = tid & 63;
    float s = 0.f;
    #pragma unroll
    for (int b = 0; b < 8; ++b) s += part[(size_t)(b * 64 + lane) * FD + col];
    #pragma unroll
    for (int off = 32; off; off >>= 1) s += __shfl_down(s, off);
    if (lane == 0) vec[col] = s;
}

// out[row] = (u + (f1*(emb'_row . v) - u^2)/N)/N
__global__ void k_out(const float* __restrict__ emb, const float* __restrict__ nrm1,
                      const float* __restrict__ scal, const float* __restrict__ fpart1,
                      const float* __restrict__ vvec, const float* __restrict__ u,
                      float* __restrict__ out) {
    __shared__ float l[256];
    __shared__ float vsh[FD];
    float A, B, AB, kap;
    red1_scal(fpart1, scal, l, A, B, AB, kap);
    int tid = threadIdx.x;
    int r0 = blockIdx.x * 16;
    vsh[tid] = vvec[tid];
    __syncthreads();
    const int wave = tid >> 6, lane = tid & 63;
    const float invN = 1.0f / NROW;
    float4 vv = *(const float4*)&vsh[lane*4];
    #pragma unroll
    for (int jj = 0; jj < 4; ++jj) {
        int row = r0 + wave * 4 + jj;
        float4 ev = *(const float4*)&emb[(size_t)row * FD + lane*4];
        float s = wred(dot4(ev, vv));
        if (lane == 0 && row < NROW - 1) {
            float f = A - kap * nrm1[row];
            float uj = u[row];
            out[row] = (uj + (f * s - uj * uj) * invN) * invN;
        }
    }
}

extern "C" void kernel_launch(void* const* d_in, const int* in_sizes, int n_in,
                              void* d_out, int out_size, void* d_ws, size_t ws_size,
                              hipStream_t stream) {
    const float* X      = (const float*)d_in[0];
    // d_in[1] = coefs (unused by the reference forward)
    const float* linear = (const float*)d_in[2];
    const float* dirv   = (const float*)d_in[3];
    const float* feat   = (const float*)d_in[4];
    float* out = (float*)d_out;

    char* ws = (char*)d_ws;
    float* scal   = (float*)(ws + 0);
    float* nrm0   = (float*)(ws + 4096);
    float* nrm1   = (float*)(ws + 36864);
    float* fpart  = (float*)(ws + 69632);
    float* fpart1 = (float*)(ws + 77824);
    float* c0     = (float*)(ws + 78848);
    float* svec   = (float*)(ws + 79872);
    float* vvec   = (float*)(ws + 80896);
    float* u      = (float*)(ws + 81920);
    float* f0     = (float*)(ws + 114688);
    float* cpart  = (float*)(ws + 147456);
    u16*   Gbf    = (u16*)  (ws + 278528);
    float* cpart1 = (float*)(ws + 409600);
    float* wpart1 = (float*)(ws + 671744);
    float* vpart  = (float*)(ws + 933888);
    u16*   Rbf    = (u16*)  (ws + 2097152);
    u16*   Rt     = (u16*)  (ws + 6291456);
    float* Gp     = (float*)(ws + 10485760);
    float* emb    = (float*)(ws + 18874368);

    k_norm<<<NROW/4, 256, 0, stream>>>(X, nrm0, fpart);
    k_prep<<<128, 256, 0, stream>>>(X, nrm0, fpart, linear, dirv, feat,
                                    scal, f0, Rbf, Rt, cpart);
    k_gram<<<dim3(4,4,NZ), 256, 0, stream>>>(Rt, Gp);
    k_gred<<<257, 256, 0, stream>>>(Gp, cpart, Gbf, c0);
    k_apply<<<256, 256, 0, stream>>>(X, Rbf, Gbf, f0, c0, emb, nrm1,
                                     fpart1, cpart1, wpart1);
    k_sv<<<64, 256, 0, stream>>>(fpart1, scal, cpart1, wpart1, svec);
    k_uv<<<NROW/16, 256, 0, stream>>>(emb, nrm1, scal, fpart1, svec, u, vpart);
    k_vred<<<64, 256, 0, stream>>>(vpart, vvec);
    k_out<<<NROW/16, 256, 0, stream>>>(emb, nrm1, scal, fpart1, vvec, u, out);
}